// Round 7
// baseline (244.022 us; speedup 1.0000x reference)
//
#include <hip/hip_runtime.h>

#define IN_DIM 256
#define HID 32
#define HEADS 4
#define F1 128   // HEADS*HID
#define BSHIFT 9           // 512 nodes per coarse bucket
#define MAXBUK 128         // LDS sizing (actual nbuk = 98 for N=50000)

static __device__ __forceinline__ float leaky(float x){ return x > 0.f ? x : 0.2f*x; }
static __device__ __forceinline__ float elu(float x){ return x > 0.f ? x : (__expf(x) - 1.f); }

// bf16 helpers (round-to-nearest-even)
static __device__ __forceinline__ unsigned short f2bf(float f){
  unsigned int u = __float_as_uint(f);
  u += 0x7FFFu + ((u >> 16) & 1u);
  return (unsigned short)(u >> 16);
}
static __device__ __forceinline__ float bf2f(unsigned short h){
  return __uint_as_float(((unsigned int)h) << 16);
}
static __device__ __forceinline__ unsigned int pack2(unsigned short a, unsigned short b){
  return (unsigned int)a | ((unsigned int)b << 16);
}
static __device__ __forceinline__ float bflo(unsigned int u){ return __uint_as_float(u << 16); }
static __device__ __forceinline__ float bfhi(unsigned int u){ return __uint_as_float(u & 0xFFFF0000u); }

__device__ __forceinline__ int block_excl_scan(int v, int tid, int* total){
  __shared__ int ws[8];
  int lane = tid & 63, w = tid >> 6;
  int incl = v;
  #pragma unroll
  for (int d = 1; d < 64; d <<= 1){ int o = __shfl_up(incl, d); if (lane >= d) incl += o; }
  if (lane == 63) ws[w] = incl;
  __syncthreads();
  if (tid == 0){ int s = 0; for (int i = 0; i < 4; ++i){ int t = ws[i]; ws[i] = s; s += t; } ws[4] = s; }
  __syncthreads();
  *total = ws[4];
  int e = ws[w] + incl - v;   // exclusive
  __syncthreads();            // allow reuse of ws in loops
  return e;
}

// ---------------- CSR build: deterministic two-level bucket sort ----------------
__global__ __launch_bounds__(256) void bukcnt_kernel(const int* __restrict__ dsts,
    int* __restrict__ cnt_blk, int E, int nbuk, int stride){
  __shared__ int lcnt[MAXBUK];
  int tid = threadIdx.x, blk = blockIdx.x;
  if (tid < nbuk) lcnt[tid] = 0;
  __syncthreads();
  int base = blk*2048;
  #pragma unroll
  for (int j = 0; j < 8; ++j){
    int i = base + tid + j*256;
    if (i < E) atomicAdd(&lcnt[dsts[i] >> BSHIFT], 1);
  }
  __syncthreads();
  if (tid < nbuk) cnt_blk[tid*stride + blk] = lcnt[tid];
}

__global__ __launch_bounds__(256) void bukscan1_kernel(int* __restrict__ cnt_blk,
    int* __restrict__ btot, int nchk, int stride){
  int b = blockIdx.x, tid = threadIdx.x;
  int carry = 0;
  for (int s = 0; s < nchk; s += 256){
    int i = s + tid;
    int v = (i < nchk) ? cnt_blk[b*stride + i] : 0;
    int tot; int e = block_excl_scan(v, tid, &tot);
    if (i < nchk) cnt_blk[b*stride + i] = carry + e;
    carry += tot;
  }
  if (tid == 0) btot[b] = carry;
}

__global__ __launch_bounds__(256) void bukscan2_kernel(const int* __restrict__ btot,
    int* __restrict__ bucket_base, int* __restrict__ offs, int nbuk, int Nn, int E){
  int tid = threadIdx.x;
  int v = (tid < nbuk) ? btot[tid] : 0;
  int tot; int e = block_excl_scan(v, tid, &tot);
  if (tid <= nbuk) bucket_base[tid] = e;
  if (tid == 0) offs[Nn] = E;
}

// passB: scatter packed (src | localdst<<16) into bucket-sorted intermediate.
// NOTE: relies on N < 65536 (src fits 16 bits) and 512-node buckets (9 bits).
__global__ __launch_bounds__(256) void bukscat_kernel(const int* __restrict__ srcs,
    const int* __restrict__ dsts, const int* __restrict__ cnt_blk,
    const int* __restrict__ bucket_base, unsigned int* __restrict__ im,
    int E, int nbuk, int stride){
  __shared__ int lcur[MAXBUK];
  int tid = threadIdx.x, blk = blockIdx.x;
  if (tid < nbuk) lcur[tid] = bucket_base[tid] + cnt_blk[tid*stride + blk];
  __syncthreads();
  int base = blk*2048;
  #pragma unroll
  for (int j = 0; j < 8; ++j){
    int i = base + tid + j*256;
    if (i < E){
      int s = srcs[i], d = dsts[i];
      int r = atomicAdd(&lcur[d >> BSHIFT], 1);
      im[r] = (unsigned)s | (((unsigned)d & 511u) << 16);
    }
  }
}

// passC: per-bucket fine sort (all LDS); csr window contiguous per bucket
__global__ __launch_bounds__(256) void bukfine_kernel(const unsigned int* __restrict__ im,
    const int* __restrict__ bucket_base, int* __restrict__ offs, int* __restrict__ csr, int Nn){
  __shared__ int lcnt[512], lpfx[512];
  int b = blockIdx.x, tid = threadIdx.x;
  int node0 = b << BSHIFT;
  int nn = min(512, Nn - node0);
  lcnt[tid] = 0; lcnt[tid+256] = 0;
  __syncthreads();
  int ebeg = bucket_base[b], eend = bucket_base[b+1];
  for (int i = ebeg + tid; i < eend; i += 256)
    atomicAdd(&lcnt[im[i] >> 16], 1);
  __syncthreads();
  int carry = 0;
  for (int s = 0; s < 512; s += 256){
    int v = lcnt[s + tid];
    int tot; int e = block_excl_scan(v, tid, &tot);
    lpfx[s + tid] = carry + e;
    carry += tot;
  }
  __syncthreads();
  if (tid < nn) offs[node0 + tid] = ebeg + lpfx[tid];
  if (tid + 256 < nn) offs[node0 + tid + 256] = ebeg + lpfx[tid + 256];
  lcnt[tid] = ebeg + lpfx[tid];
  lcnt[tid+256] = ebeg + lpfx[tid+256];
  __syncthreads();
  for (int i = ebeg + tid; i < eend; i += 256){
    unsigned int u = im[i];
    int pos = atomicAdd(&lcnt[u >> 16], 1);
    csr[pos] = (int)(u & 0xFFFFu);
  }
}

// ---------------- W1 convert: f32 [k][n] -> bf16 hi/lo transposed [n][k] ----------------
__global__ __launch_bounds__(256) void convw_kernel(const float* __restrict__ W1,
    unsigned short* __restrict__ Wh, unsigned short* __restrict__ Wl){
  int i = blockIdx.x*256 + threadIdx.x;      // 0..32767
  int n = i >> 8, k = i & 255;
  float w = W1[(size_t)k*F1 + n];
  unsigned short h = f2bf(w);
  Wh[i] = h;
  Wl[i] = f2bf(w - bf2f(h));
}

// ---------------- GEMM1 (MFMA bf16 split): h1(bf16) = x @ W1, fused att coefficients ----------------
typedef __attribute__((ext_vector_type(8))) short bf8_t;
typedef __attribute__((ext_vector_type(4))) float f4_t;

__global__ __launch_bounds__(256) void gemm1_kernel(const float* __restrict__ x,
    const unsigned short* __restrict__ Wh, const unsigned short* __restrict__ Wl,
    const float* __restrict__ att_src, const float* __restrict__ att_dst,
    unsigned short* __restrict__ h1b, float* __restrict__ as1, float* __restrict__ ad1, int M){
  __shared__ uint4 AhV[64][5], AlV[64][5];    // [row][k-chunk], 80B rows (2-way only = free)
  __shared__ uint4 BhV[128][5], BlV[128][5];  // [n][k-chunk]
  const int tid = threadIdx.x;
  const int m0 = blockIdx.x*64;
  const int wave = tid >> 6, lane = tid & 63;
  const int quad = lane >> 4, l16 = lane & 15;
  const int wr = (wave & 1)*32;
  const int wc = (wave >> 1)*64;
  f4_t acc[2][4];
  #pragma unroll
  for (int r = 0; r < 2; ++r)
    #pragma unroll
    for (int c = 0; c < 4; ++c)
      #pragma unroll
      for (int i = 0; i < 4; ++i) acc[r][c][i] = 0.f;

  const int ar = tid >> 2, akc = tid & 3;
  const bool aok = (m0 + ar) < M;
  const float* ap = x + (size_t)(m0 + ar)*IN_DIM + 8*akc;
  const int bn = tid >> 1, bkc = (tid & 1)*2;
  const unsigned short* bph = Wh + (size_t)bn*256 + 16*(tid & 1);
  const unsigned short* bpl = Wl + (size_t)bn*256 + 16*(tid & 1);

  for (int k0 = 0; k0 < IN_DIM; k0 += 32){
    float4 a0 = make_float4(0.f,0.f,0.f,0.f), a1 = a0;
    if (aok){ a0 = *(const float4*)(ap + k0); a1 = *(const float4*)(ap + k0 + 4); }
    float v[8] = {a0.x,a0.y,a0.z,a0.w,a1.x,a1.y,a1.z,a1.w};
    unsigned short hh[8], ll[8];
    #pragma unroll
    for (int j = 0; j < 8; ++j){
      unsigned short h = f2bf(v[j]); hh[j] = h; ll[j] = f2bf(v[j] - bf2f(h));
    }
    uint4 hv; hv.x = pack2(hh[0],hh[1]); hv.y = pack2(hh[2],hh[3]); hv.z = pack2(hh[4],hh[5]); hv.w = pack2(hh[6],hh[7]);
    uint4 lv; lv.x = pack2(ll[0],ll[1]); lv.y = pack2(ll[2],ll[3]); lv.z = pack2(ll[4],ll[5]); lv.w = pack2(ll[6],ll[7]);
    AhV[ar][akc] = hv;
    AlV[ar][akc] = lv;
    BhV[bn][bkc+0] = *(const uint4*)(bph + k0);
    BhV[bn][bkc+1] = *(const uint4*)(bph + k0 + 8);
    BlV[bn][bkc+0] = *(const uint4*)(bpl + k0);
    BlV[bn][bkc+1] = *(const uint4*)(bpl + k0 + 8);
    __syncthreads();

    bf8_t arh[2], arl[2], brh[4], brl[4];
    #pragma unroll
    for (int r = 0; r < 2; ++r){
      arh[r] = *(const bf8_t*)&AhV[wr + r*16 + l16][quad];
      arl[r] = *(const bf8_t*)&AlV[wr + r*16 + l16][quad];
    }
    #pragma unroll
    for (int c = 0; c < 4; ++c){
      brh[c] = *(const bf8_t*)&BhV[wc + c*16 + l16][quad];
      brl[c] = *(const bf8_t*)&BlV[wc + c*16 + l16][quad];
    }
    #pragma unroll
    for (int r = 0; r < 2; ++r)
      #pragma unroll
      for (int c = 0; c < 4; ++c){
        acc[r][c] = __builtin_amdgcn_mfma_f32_16x16x32_bf16(arh[r], brh[c], acc[r][c], 0, 0, 0);
        acc[r][c] = __builtin_amdgcn_mfma_f32_16x16x32_bf16(arh[r], brl[c], acc[r][c], 0, 0, 0);
        acc[r][c] = __builtin_amdgcn_mfma_f32_16x16x32_bf16(arl[r], brh[c], acc[r][c], 0, 0, 0);
      }
    __syncthreads();
  }

  const int head0 = wc >> 5;
  float sv[4], dv[4];
  #pragma unroll
  for (int c = 0; c < 4; ++c){
    int col_in_head = (c & 1)*16 + l16;
    sv[c] = att_src[(head0 + (c >> 1))*HID + col_in_head];
    dv[c] = att_dst[(head0 + (c >> 1))*HID + col_in_head];
  }
  #pragma unroll
  for (int r = 0; r < 2; ++r){
    #pragma unroll
    for (int i = 0; i < 4; ++i){
      int row = m0 + wr + r*16 + quad*4 + i;
      bool ok = row < M;
      float hv0 = acc[r][0][i], hv1 = acc[r][1][i], hv2 = acc[r][2][i], hv3 = acc[r][3][i];
      if (ok){
        unsigned short* hp = h1b + (size_t)row*F1 + wc + l16;
        hp[0]  = f2bf(hv0); hp[16] = f2bf(hv1); hp[32] = f2bf(hv2); hp[48] = f2bf(hv3);
      }
      float p0 = hv0*sv[0] + hv1*sv[1];
      float p1 = hv2*sv[2] + hv3*sv[3];
      float q0 = hv0*dv[0] + hv1*dv[1];
      float q1 = hv2*dv[2] + hv3*dv[3];
      p0 += __shfl_xor(p0,1); p0 += __shfl_xor(p0,2); p0 += __shfl_xor(p0,4); p0 += __shfl_xor(p0,8);
      p1 += __shfl_xor(p1,1); p1 += __shfl_xor(p1,2); p1 += __shfl_xor(p1,4); p1 += __shfl_xor(p1,8);
      q0 += __shfl_xor(q0,1); q0 += __shfl_xor(q0,2); q0 += __shfl_xor(q0,4); q0 += __shfl_xor(q0,8);
      q1 += __shfl_xor(q1,1); q1 += __shfl_xor(q1,2); q1 += __shfl_xor(q1,4); q1 += __shfl_xor(q1,8);
      if (ok && l16 == 0){
        as1[row*4 + head0]     = p0;
        as1[row*4 + head0 + 1] = p1;
        ad1[row*4 + head0]     = q0;
        ad1[row*4 + head0 + 1] = q1;
      }
    }
  }
}

// ---------------- Aggregation 1 (bf16 h1 gather, bf16 h1a output) ----------------
__global__ __launch_bounds__(256) void agg1_kernel(const unsigned int* __restrict__ h1b,
    const float* __restrict__ a_s1, const float* __restrict__ a_d1,
    const int* __restrict__ offs, const int* __restrict__ csr,
    const float* __restrict__ b1, uint4* __restrict__ h1a4, int N){
  int n = blockIdx.x*4 + (threadIdx.x >> 6);
  if (n >= N) return;
  const int lane = threadIdx.x & 63;
  const int sub  = lane >> 4;       // edge subgroup 0..3
  const int cl   = lane & 15;       // channel-lane
  const int head = cl >> 2;
  const float ad = a_d1[n*4+head];
  const int cw = 4*cl;
  float a0=0,a1=0,a2=0,a3=0,a4=0,a5=0,a6=0,a7=0,den=0;
  if (sub == 0){ // self loop
    float p = __expf(leaky(a_s1[n*4+head] + ad));
    uint4 u = *(const uint4*)(h1b + (size_t)n*64 + cw);
    a0 = p*bflo(u.x); a1 = p*bfhi(u.x); a2 = p*bflo(u.y); a3 = p*bfhi(u.y);
    a4 = p*bflo(u.z); a5 = p*bfhi(u.z); a6 = p*bflo(u.w); a7 = p*bfhi(u.w);
    den = p;
  }
  const int beg = offs[n], end = offs[n+1];
  int e = beg + sub;
  for (; e + 12 < end; e += 16){
    int s0 = csr[e], s1 = csr[e+4], s2 = csr[e+8], s3 = csr[e+12];
    float p0 = __expf(leaky(a_s1[s0*4+head] + ad));
    float p1 = __expf(leaky(a_s1[s1*4+head] + ad));
    float p2 = __expf(leaky(a_s1[s2*4+head] + ad));
    float p3 = __expf(leaky(a_s1[s3*4+head] + ad));
    uint4 u0 = *(const uint4*)(h1b + (size_t)s0*64 + cw);
    uint4 u1 = *(const uint4*)(h1b + (size_t)s1*64 + cw);
    uint4 u2 = *(const uint4*)(h1b + (size_t)s2*64 + cw);
    uint4 u3 = *(const uint4*)(h1b + (size_t)s3*64 + cw);
    a0 += p0*bflo(u0.x) + p1*bflo(u1.x) + p2*bflo(u2.x) + p3*bflo(u3.x);
    a1 += p0*bfhi(u0.x) + p1*bfhi(u1.x) + p2*bfhi(u2.x) + p3*bfhi(u3.x);
    a2 += p0*bflo(u0.y) + p1*bflo(u1.y) + p2*bflo(u2.y) + p3*bflo(u3.y);
    a3 += p0*bfhi(u0.y) + p1*bfhi(u1.y) + p2*bfhi(u2.y) + p3*bfhi(u3.y);
    a4 += p0*bflo(u0.z) + p1*bflo(u1.z) + p2*bflo(u2.z) + p3*bflo(u3.z);
    a5 += p0*bfhi(u0.z) + p1*bfhi(u1.z) + p2*bfhi(u2.z) + p3*bfhi(u3.z);
    a6 += p0*bflo(u0.w) + p1*bflo(u1.w) + p2*bflo(u2.w) + p3*bflo(u3.w);
    a7 += p0*bfhi(u0.w) + p1*bfhi(u1.w) + p2*bfhi(u2.w) + p3*bfhi(u3.w);
    den += p0 + p1 + p2 + p3;
  }
  for (; e < end; e += 4){
    int s = csr[e];
    float p = __expf(leaky(a_s1[s*4+head] + ad));
    uint4 u = *(const uint4*)(h1b + (size_t)s*64 + cw);
    a0 += p*bflo(u.x); a1 += p*bfhi(u.x); a2 += p*bflo(u.y); a3 += p*bfhi(u.y);
    a4 += p*bflo(u.z); a5 += p*bfhi(u.z); a6 += p*bflo(u.w); a7 += p*bfhi(u.w);
    den += p;
  }
  #pragma unroll
  for (int off = 16; off < 64; off <<= 1){
    a0 += __shfl_xor(a0,off); a1 += __shfl_xor(a1,off);
    a2 += __shfl_xor(a2,off); a3 += __shfl_xor(a3,off);
    a4 += __shfl_xor(a4,off); a5 += __shfl_xor(a5,off);
    a6 += __shfl_xor(a6,off); a7 += __shfl_xor(a7,off);
    den += __shfl_xor(den,off);
  }
  if (sub == 0){
    float inv = 1.f/den;
    int ch = 8*cl;
    float4 b0 = *(const float4*)(b1 + ch);
    float4 b4 = *(const float4*)(b1 + ch + 4);
    uint4 w;
    w.x = pack2(f2bf(elu(a0*inv+b0.x)), f2bf(elu(a1*inv+b0.y)));
    w.y = pack2(f2bf(elu(a2*inv+b0.z)), f2bf(elu(a3*inv+b0.w)));
    w.z = pack2(f2bf(elu(a4*inv+b4.x)), f2bf(elu(a5*inv+b4.y)));
    w.w = pack2(f2bf(elu(a6*inv+b4.z)), f2bf(elu(a7*inv+b4.w)));
    h1a4[(size_t)n*16 + cl] = w;
  }
}

// ---------------- GEMM2: h2(bf16) = h1a(bf16) @ W2, fused att coefficients ----------------
__global__ __launch_bounds__(256) void gemm2_kernel(const uint4* __restrict__ h1a4, const float* __restrict__ W2,
    const float* __restrict__ att_src, const float* __restrict__ att_dst,
    unsigned int* __restrict__ h2b, float* __restrict__ as2, float* __restrict__ ad2, int M){
  __shared__ float As[64*132];
  __shared__ float Ws[128*32];
  const int tid = threadIdx.x;
  const int cg = tid & 15;
  const int rg = tid >> 4;
  const int m0 = blockIdx.x*64;
  #pragma unroll
  for (int p = 0; p < 4; ++p){
    int j = tid + 256*p;        // 0..1023
    int r = j >> 4, q = j & 15;
    int row = m0 + r;
    uint4 u = make_uint4(0,0,0,0);
    if (row < M) u = h1a4[(size_t)row*16 + q];
    float4 f0 = make_float4(bflo(u.x), bfhi(u.x), bflo(u.y), bfhi(u.y));
    float4 f1 = make_float4(bflo(u.z), bfhi(u.z), bflo(u.w), bfhi(u.w));
    *(float4*)&As[r*132 + 8*q]     = f0;
    *(float4*)&As[r*132 + 8*q + 4] = f1;
  }
  #pragma unroll
  for (int p = 0; p < 4; ++p){
    int i = tid + 256*p;
    ((float4*)Ws)[i] = ((const float4*)W2)[i];
  }
  __syncthreads();
  float acc[4][2] = {};
  const float* a0p = &As[(4*rg+0)*132];
  const float* a1p = &As[(4*rg+1)*132];
  const float* a2p = &As[(4*rg+2)*132];
  const float* a3p = &As[(4*rg+3)*132];
  #pragma unroll 8
  for (int kk = 0; kk < 128; ++kk){
    float2 w = *(const float2*)&Ws[kk*32 + 2*cg];
    float a0 = a0p[kk], a1 = a1p[kk], a2 = a2p[kk], a3 = a3p[kk];
    acc[0][0]+=a0*w.x; acc[0][1]+=a0*w.y;
    acc[1][0]+=a1*w.x; acc[1][1]+=a1*w.y;
    acc[2][0]+=a2*w.x; acc[2][1]+=a2*w.y;
    acc[3][0]+=a3*w.x; acc[3][1]+=a3*w.y;
  }
  const float2 sv = *(const float2*)(att_src + 2*cg);
  const float2 dv = *(const float2*)(att_dst + 2*cg);
  #pragma unroll
  for (int i = 0; i < 4; ++i){
    int row = m0 + 4*rg + i;
    if (row < M){
      float2 o = make_float2(acc[i][0], acc[i][1]);
      h2b[(size_t)row*16 + cg] = pack2(f2bf(o.x), f2bf(o.y));
      float ps = o.x*sv.x + o.y*sv.y;
      float pd = o.x*dv.x + o.y*dv.y;
      ps += __shfl_xor(ps,1); ps += __shfl_xor(ps,2); ps += __shfl_xor(ps,4); ps += __shfl_xor(ps,8);
      pd += __shfl_xor(pd,1); pd += __shfl_xor(pd,2); pd += __shfl_xor(pd,4); pd += __shfl_xor(pd,8);
      if (cg == 0){ as2[row] = ps; ad2[row] = pd; }
    }
  }
}

// ---------------- Aggregation 2 + bias + elu + final linear (bf16 h2 gather) ----------------
__global__ __launch_bounds__(256) void agg2_kernel(const unsigned int* __restrict__ h2b,
    const float* __restrict__ as2, const float* __restrict__ ad2,
    const int* __restrict__ offs, const int* __restrict__ csr,
    const float* __restrict__ b2, const float* __restrict__ linw, const float* __restrict__ linb,
    float* __restrict__ out, int N){
  int n = blockIdx.x*4 + (threadIdx.x >> 6);
  if (n >= N) return;
  const int lane = threadIdx.x & 63;
  const int sub  = lane >> 3;
  const int cl   = lane & 7;
  const int cw   = 2*cl;
  const float ad = ad2[n];
  float a0=0,a1=0,a2=0,a3=0,den=0;
  if (sub == 0){
    float p = __expf(leaky(as2[n] + ad));
    uint2 u = *(const uint2*)(h2b + (size_t)n*16 + cw);
    a0 = p*bflo(u.x); a1 = p*bfhi(u.x); a2 = p*bflo(u.y); a3 = p*bfhi(u.y);
    den = p;
  }
  const int beg = offs[n], end = offs[n+1];
  int e = beg + sub;
  for (; e + 24 < end; e += 32){
    int s0 = csr[e], s1 = csr[e+8], s2 = csr[e+16], s3 = csr[e+24];
    float p0 = __expf(leaky(as2[s0] + ad));
    float p1 = __expf(leaky(as2[s1] + ad));
    float p2 = __expf(leaky(as2[s2] + ad));
    float p3 = __expf(leaky(as2[s3] + ad));
    uint2 u0 = *(const uint2*)(h2b + (size_t)s0*16 + cw);
    uint2 u1 = *(const uint2*)(h2b + (size_t)s1*16 + cw);
    uint2 u2 = *(const uint2*)(h2b + (size_t)s2*16 + cw);
    uint2 u3 = *(const uint2*)(h2b + (size_t)s3*16 + cw);
    a0 += p0*bflo(u0.x) + p1*bflo(u1.x) + p2*bflo(u2.x) + p3*bflo(u3.x);
    a1 += p0*bfhi(u0.x) + p1*bfhi(u1.x) + p2*bfhi(u2.x) + p3*bfhi(u3.x);
    a2 += p0*bflo(u0.y) + p1*bflo(u1.y) + p2*bflo(u2.y) + p3*bflo(u3.y);
    a3 += p0*bfhi(u0.y) + p1*bfhi(u1.y) + p2*bfhi(u2.y) + p3*bfhi(u3.y);
    den += p0 + p1 + p2 + p3;
  }
  for (; e < end; e += 8){
    int s = csr[e];
    float p = __expf(leaky(as2[s] + ad));
    uint2 u = *(const uint2*)(h2b + (size_t)s*16 + cw);
    a0 += p*bflo(u.x); a1 += p*bfhi(u.x); a2 += p*bflo(u.y); a3 += p*bfhi(u.y);
    den += p;
  }
  #pragma unroll
  for (int off = 8; off < 64; off <<= 1){
    a0 += __shfl_xor(a0,off); a1 += __shfl_xor(a1,off);
    a2 += __shfl_xor(a2,off); a3 += __shfl_xor(a3,off);
    den += __shfl_xor(den,off);
  }
  float inv = 1.f/den;
  int ch = 4*cl;
  float o0 = elu(a0*inv + b2[ch+0]);
  float o1 = elu(a1*inv + b2[ch+1]);
  float o2 = elu(a2*inv + b2[ch+2]);
  float o3 = elu(a3*inv + b2[ch+3]);
  float r0 = o0*linw[2*(ch+0)]   + o1*linw[2*(ch+1)]   + o2*linw[2*(ch+2)]   + o3*linw[2*(ch+3)];
  float r1 = o0*linw[2*(ch+0)+1] + o1*linw[2*(ch+1)+1] + o2*linw[2*(ch+2)+1] + o3*linw[2*(ch+3)+1];
  r0 += __shfl_xor(r0,1); r0 += __shfl_xor(r0,2); r0 += __shfl_xor(r0,4);
  r1 += __shfl_xor(r1,1); r1 += __shfl_xor(r1,2); r1 += __shfl_xor(r1,4);
  if (lane == 0){
    out[(size_t)n*2+0] = r0 + linb[0];
    out[(size_t)n*2+1] = r1 + linb[1];
  }
}

// ---------------- launch ----------------
extern "C" void kernel_launch(void* const* d_in, const int* in_sizes, int n_in,
                              void* d_out, int out_size, void* d_ws, size_t ws_size,
                              hipStream_t stream) {
  const float* x    = (const float*)d_in[0];
  const int*   ei   = (const int*)  d_in[1];
  const float* W1   = (const float*)d_in[2];
  const float* as1w = (const float*)d_in[3];
  const float* ad1w = (const float*)d_in[4];
  const float* b1   = (const float*)d_in[5];
  const float* W2   = (const float*)d_in[6];
  const float* as2w = (const float*)d_in[7];
  const float* ad2w = (const float*)d_in[8];
  const float* b2   = (const float*)d_in[9];
  const float* linw = (const float*)d_in[10];
  const float* linb = (const float*)d_in[11];
  float* out = (float*)d_out;

  const int N = in_sizes[0] / IN_DIM;   // 50000
  const int E = in_sizes[1] / 2;        // 800000

  const int NBUK = (N + 511) >> BSHIFT;           // 98
  const int NCHK = (E + 2047) / 2048;             // 391
  const int CSTR = (NCHK + 3) & ~3;               // padded stride

  char* ws = (char*)d_ws;
  auto alloc = [&](size_t bytes) -> char* {
    char* p = ws; ws += (bytes + 255) & ~(size_t)255; return p;
  };
  unsigned short* h1b = (unsigned short*)alloc((size_t)N*F1*2);  // bf16; also hosts im during sort
  uint4* h1a4 = (uint4*)alloc((size_t)N*F1*2);                   // bf16 packed
  unsigned int* h2b = (unsigned int*)alloc((size_t)N*HID*2);     // bf16 packed
  float* a_s1 = (float*)alloc((size_t)N*4*4);
  float* a_d1 = (float*)alloc((size_t)N*4*4);
  float* a_s2 = (float*)alloc((size_t)N*4);
  float* a_d2 = (float*)alloc((size_t)N*4);
  size_t cntblk_bytes = (size_t)NBUK*CSTR*4;
  if (cntblk_bytes < 131072) cntblk_bytes = 131072;
  int* cnt_blk = (int*)alloc(cntblk_bytes);        // also hosts W1h/W1l after passB
  int* btot    = (int*)alloc((size_t)(NBUK+1)*4);
  int* bbase   = (int*)alloc((size_t)(NBUK+1)*4);
  int* offs    = (int*)alloc((size_t)(N+1)*4);
  int* csr     = (int*)alloc((size_t)E*4);
  // aliases (lifetimes disjoint by kernel ordering on the stream):
  unsigned int* im = (unsigned int*)h1b;           // sort intermediate, dead before gemm1 writes h1b
  unsigned short* W1h = (unsigned short*)cnt_blk;  // cnt_blk dead after bukscat
  unsigned short* W1l = W1h + (size_t)IN_DIM*F1;

  const int* srcs = ei;       // edge_index[0]
  const int* dsts = ei + E;   // edge_index[1]

  bukcnt_kernel<<<NCHK, 256, 0, stream>>>(dsts, cnt_blk, E, NBUK, CSTR);
  bukscan1_kernel<<<NBUK, 256, 0, stream>>>(cnt_blk, btot, NCHK, CSTR);
  bukscan2_kernel<<<1, 256, 0, stream>>>(btot, bbase, offs, NBUK, N, E);
  bukscat_kernel<<<NCHK, 256, 0, stream>>>(srcs, dsts, cnt_blk, bbase, im, E, NBUK, CSTR);
  bukfine_kernel<<<NBUK, 256, 0, stream>>>(im, bbase, offs, csr, N);
  convw_kernel<<<(IN_DIM*F1)/256, 256, 0, stream>>>(W1, W1h, W1l);
  gemm1_kernel<<<(N+63)/64, 256, 0, stream>>>(x, W1h, W1l, as1w, ad1w, h1b, a_s1, a_d1, N);
  agg1_kernel<<<(N+3)/4, 256, 0, stream>>>((const unsigned int*)h1b, a_s1, a_d1, offs, csr, b1, h1a4, N);
  gemm2_kernel<<<(N+63)/64, 256, 0, stream>>>(h1a4, W2, as2w, ad2w, h2b, a_s2, a_d2, N);
  agg2_kernel<<<(N+3)/4, 256, 0, stream>>>(h2b, a_s2, a_d2, offs, csr, b2, linw, linb, out, N);
}

// Round 8
// 242.751 us; speedup vs baseline: 1.0052x; 1.0052x over previous
//
#include <hip/hip_runtime.h>
#include <hip/hip_fp16.h>

#define IN_DIM 256
#define HID 32
#define HEADS 4
#define F1 128   // HEADS*HID
#define BSHIFT 9           // 512 nodes per coarse bucket
#define MAXBUK 128         // LDS sizing (actual nbuk = 98 for N=50000)

static __device__ __forceinline__ float leaky(float x){ return x > 0.f ? x : 0.2f*x; }
static __device__ __forceinline__ float elu(float x){ return x > 0.f ? x : (__expf(x) - 1.f); }

// bf16 helpers (round-to-nearest-even) — used for the GEMM1 MFMA split only
static __device__ __forceinline__ unsigned short f2bf(float f){
  unsigned int u = __float_as_uint(f);
  u += 0x7FFFu + ((u >> 16) & 1u);
  return (unsigned short)(u >> 16);
}
static __device__ __forceinline__ float bf2f(unsigned short h){
  return __uint_as_float(((unsigned int)h) << 16);
}
static __device__ __forceinline__ unsigned int pack2(unsigned short a, unsigned short b){
  return (unsigned int)a | ((unsigned int)b << 16);
}
// f16 helpers — activation storage (v_fma_mix-friendly unpack)
static __device__ __forceinline__ unsigned short f2h(float f){
  return __half_as_ushort(__float2half(f));
}
static __device__ __forceinline__ float hlo(unsigned int u){
  return __half2float(__ushort_as_half((unsigned short)(u & 0xFFFFu)));
}
static __device__ __forceinline__ float hhi(unsigned int u){
  return __half2float(__ushort_as_half((unsigned short)(u >> 16)));
}

__device__ __forceinline__ int block_excl_scan(int v, int tid, int* total){
  __shared__ int ws[8];
  int lane = tid & 63, w = tid >> 6;
  int incl = v;
  #pragma unroll
  for (int d = 1; d < 64; d <<= 1){ int o = __shfl_up(incl, d); if (lane >= d) incl += o; }
  if (lane == 63) ws[w] = incl;
  __syncthreads();
  if (tid == 0){ int s = 0; for (int i = 0; i < 4; ++i){ int t = ws[i]; ws[i] = s; s += t; } ws[4] = s; }
  __syncthreads();
  *total = ws[4];
  int e = ws[w] + incl - v;   // exclusive
  __syncthreads();            // allow reuse of ws in loops
  return e;
}

// ---------------- CSR build: deterministic two-level bucket sort ----------------
__global__ __launch_bounds__(256) void bukcnt_kernel(const int* __restrict__ dsts,
    int* __restrict__ cnt_blk, int E, int nbuk, int stride){
  __shared__ int lcnt[MAXBUK];
  int tid = threadIdx.x, blk = blockIdx.x;
  if (tid < nbuk) lcnt[tid] = 0;
  __syncthreads();
  int base = blk*2048;
  #pragma unroll
  for (int j = 0; j < 8; ++j){
    int i = base + tid + j*256;
    if (i < E) atomicAdd(&lcnt[dsts[i] >> BSHIFT], 1);
  }
  __syncthreads();
  if (tid < nbuk) cnt_blk[tid*stride + blk] = lcnt[tid];
}

__global__ __launch_bounds__(256) void bukscan1_kernel(int* __restrict__ cnt_blk,
    int* __restrict__ btot, int nchk, int stride){
  int b = blockIdx.x, tid = threadIdx.x;
  int carry = 0;
  for (int s = 0; s < nchk; s += 256){
    int i = s + tid;
    int v = (i < nchk) ? cnt_blk[b*stride + i] : 0;
    int tot; int e = block_excl_scan(v, tid, &tot);
    if (i < nchk) cnt_blk[b*stride + i] = carry + e;
    carry += tot;
  }
  if (tid == 0) btot[b] = carry;
}

__global__ __launch_bounds__(256) void bukscan2_kernel(const int* __restrict__ btot,
    int* __restrict__ bucket_base, int* __restrict__ offs, int nbuk, int Nn, int E){
  int tid = threadIdx.x;
  int v = (tid < nbuk) ? btot[tid] : 0;
  int tot; int e = block_excl_scan(v, tid, &tot);
  if (tid <= nbuk) bucket_base[tid] = e;
  if (tid == 0) offs[Nn] = E;
}

// passB: scatter packed (src | localdst<<16); relies on N < 65536, 512-node buckets
__global__ __launch_bounds__(256) void bukscat_kernel(const int* __restrict__ srcs,
    const int* __restrict__ dsts, const int* __restrict__ cnt_blk,
    const int* __restrict__ bucket_base, unsigned int* __restrict__ im,
    int E, int nbuk, int stride){
  __shared__ int lcur[MAXBUK];
  int tid = threadIdx.x, blk = blockIdx.x;
  if (tid < nbuk) lcur[tid] = bucket_base[tid] + cnt_blk[tid*stride + blk];
  __syncthreads();
  int base = blk*2048;
  #pragma unroll
  for (int j = 0; j < 8; ++j){
    int i = base + tid + j*256;
    if (i < E){
      int s = srcs[i], d = dsts[i];
      int r = atomicAdd(&lcur[d >> BSHIFT], 1);
      im[r] = (unsigned)s | (((unsigned)d & 511u) << 16);
    }
  }
}

// passC: per-bucket fine sort (all LDS); csr window contiguous per bucket
__global__ __launch_bounds__(256) void bukfine_kernel(const unsigned int* __restrict__ im,
    const int* __restrict__ bucket_base, int* __restrict__ offs, int* __restrict__ csr, int Nn){
  __shared__ int lcnt[512], lpfx[512];
  int b = blockIdx.x, tid = threadIdx.x;
  int node0 = b << BSHIFT;
  int nn = min(512, Nn - node0);
  lcnt[tid] = 0; lcnt[tid+256] = 0;
  __syncthreads();
  int ebeg = bucket_base[b], eend = bucket_base[b+1];
  for (int i = ebeg + tid; i < eend; i += 256)
    atomicAdd(&lcnt[im[i] >> 16], 1);
  __syncthreads();
  int carry = 0;
  for (int s = 0; s < 512; s += 256){
    int v = lcnt[s + tid];
    int tot; int e = block_excl_scan(v, tid, &tot);
    lpfx[s + tid] = carry + e;
    carry += tot;
  }
  __syncthreads();
  if (tid < nn) offs[node0 + tid] = ebeg + lpfx[tid];
  if (tid + 256 < nn) offs[node0 + tid + 256] = ebeg + lpfx[tid + 256];
  lcnt[tid] = ebeg + lpfx[tid];
  lcnt[tid+256] = ebeg + lpfx[tid+256];
  __syncthreads();
  for (int i = ebeg + tid; i < eend; i += 256){
    unsigned int u = im[i];
    int pos = atomicAdd(&lcnt[u >> 16], 1);
    csr[pos] = (int)(u & 0xFFFFu);
  }
}

// ---------------- W1 convert: f32 [k][n] -> bf16 hi/lo transposed [n][k] ----------------
__global__ __launch_bounds__(256) void convw_kernel(const float* __restrict__ W1,
    unsigned short* __restrict__ Wh, unsigned short* __restrict__ Wl){
  int i = blockIdx.x*256 + threadIdx.x;      // 0..32767
  int n = i >> 8, k = i & 255;
  float w = W1[(size_t)k*F1 + n];
  unsigned short h = f2bf(w);
  Wh[i] = h;
  Wl[i] = f2bf(w - bf2f(h));
}

// ---------------- GEMM1 (MFMA bf16 split): h1(f16) = x @ W1, fused att coefficients ----------------
typedef __attribute__((ext_vector_type(8))) short bf8_t;
typedef __attribute__((ext_vector_type(4))) float f4_t;

__global__ __launch_bounds__(256) void gemm1_kernel(const float* __restrict__ x,
    const unsigned short* __restrict__ Wh, const unsigned short* __restrict__ Wl,
    const float* __restrict__ att_src, const float* __restrict__ att_dst,
    unsigned short* __restrict__ h1b, float* __restrict__ as1, float* __restrict__ ad1, int M){
  __shared__ uint4 AhV[64][5], AlV[64][5];    // [row][k-chunk], 80B rows (2-way only = free)
  __shared__ uint4 BhV[128][5], BlV[128][5];  // [n][k-chunk]
  const int tid = threadIdx.x;
  const int m0 = blockIdx.x*64;
  const int wave = tid >> 6, lane = tid & 63;
  const int quad = lane >> 4, l16 = lane & 15;
  const int wr = (wave & 1)*32;
  const int wc = (wave >> 1)*64;
  f4_t acc[2][4];
  #pragma unroll
  for (int r = 0; r < 2; ++r)
    #pragma unroll
    for (int c = 0; c < 4; ++c)
      #pragma unroll
      for (int i = 0; i < 4; ++i) acc[r][c][i] = 0.f;

  const int ar = tid >> 2, akc = tid & 3;
  const bool aok = (m0 + ar) < M;
  const float* ap = x + (size_t)(m0 + ar)*IN_DIM + 8*akc;
  const int bn = tid >> 1, bkc = (tid & 1)*2;
  const unsigned short* bph = Wh + (size_t)bn*256 + 16*(tid & 1);
  const unsigned short* bpl = Wl + (size_t)bn*256 + 16*(tid & 1);

  for (int k0 = 0; k0 < IN_DIM; k0 += 32){
    float4 a0 = make_float4(0.f,0.f,0.f,0.f), a1 = a0;
    if (aok){ a0 = *(const float4*)(ap + k0); a1 = *(const float4*)(ap + k0 + 4); }
    float v[8] = {a0.x,a0.y,a0.z,a0.w,a1.x,a1.y,a1.z,a1.w};
    unsigned short hh[8], ll[8];
    #pragma unroll
    for (int j = 0; j < 8; ++j){
      unsigned short h = f2bf(v[j]); hh[j] = h; ll[j] = f2bf(v[j] - bf2f(h));
    }
    uint4 hv; hv.x = pack2(hh[0],hh[1]); hv.y = pack2(hh[2],hh[3]); hv.z = pack2(hh[4],hh[5]); hv.w = pack2(hh[6],hh[7]);
    uint4 lv; lv.x = pack2(ll[0],ll[1]); lv.y = pack2(ll[2],ll[3]); lv.z = pack2(ll[4],ll[5]); lv.w = pack2(ll[6],ll[7]);
    AhV[ar][akc] = hv;
    AlV[ar][akc] = lv;
    BhV[bn][bkc+0] = *(const uint4*)(bph + k0);
    BhV[bn][bkc+1] = *(const uint4*)(bph + k0 + 8);
    BlV[bn][bkc+0] = *(const uint4*)(bpl + k0);
    BlV[bn][bkc+1] = *(const uint4*)(bpl + k0 + 8);
    __syncthreads();

    bf8_t arh[2], arl[2], brh[4], brl[4];
    #pragma unroll
    for (int r = 0; r < 2; ++r){
      arh[r] = *(const bf8_t*)&AhV[wr + r*16 + l16][quad];
      arl[r] = *(const bf8_t*)&AlV[wr + r*16 + l16][quad];
    }
    #pragma unroll
    for (int c = 0; c < 4; ++c){
      brh[c] = *(const bf8_t*)&BhV[wc + c*16 + l16][quad];
      brl[c] = *(const bf8_t*)&BlV[wc + c*16 + l16][quad];
    }
    #pragma unroll
    for (int r = 0; r < 2; ++r)
      #pragma unroll
      for (int c = 0; c < 4; ++c){
        acc[r][c] = __builtin_amdgcn_mfma_f32_16x16x32_bf16(arh[r], brh[c], acc[r][c], 0, 0, 0);
        acc[r][c] = __builtin_amdgcn_mfma_f32_16x16x32_bf16(arh[r], brl[c], acc[r][c], 0, 0, 0);
        acc[r][c] = __builtin_amdgcn_mfma_f32_16x16x32_bf16(arl[r], brh[c], acc[r][c], 0, 0, 0);
      }
    __syncthreads();
  }

  const int head0 = wc >> 5;
  float sv[4], dv[4];
  #pragma unroll
  for (int c = 0; c < 4; ++c){
    int col_in_head = (c & 1)*16 + l16;
    sv[c] = att_src[(head0 + (c >> 1))*HID + col_in_head];
    dv[c] = att_dst[(head0 + (c >> 1))*HID + col_in_head];
  }
  #pragma unroll
  for (int r = 0; r < 2; ++r){
    #pragma unroll
    for (int i = 0; i < 4; ++i){
      int row = m0 + wr + r*16 + quad*4 + i;
      bool ok = row < M;
      float hv0 = acc[r][0][i], hv1 = acc[r][1][i], hv2 = acc[r][2][i], hv3 = acc[r][3][i];
      if (ok){
        unsigned short* hp = h1b + (size_t)row*F1 + wc + l16;
        hp[0]  = f2h(hv0); hp[16] = f2h(hv1); hp[32] = f2h(hv2); hp[48] = f2h(hv3);
      }
      float p0 = hv0*sv[0] + hv1*sv[1];
      float p1 = hv2*sv[2] + hv3*sv[3];
      float q0 = hv0*dv[0] + hv1*dv[1];
      float q1 = hv2*dv[2] + hv3*dv[3];
      p0 += __shfl_xor(p0,1); p0 += __shfl_xor(p0,2); p0 += __shfl_xor(p0,4); p0 += __shfl_xor(p0,8);
      p1 += __shfl_xor(p1,1); p1 += __shfl_xor(p1,2); p1 += __shfl_xor(p1,4); p1 += __shfl_xor(p1,8);
      q0 += __shfl_xor(q0,1); q0 += __shfl_xor(q0,2); q0 += __shfl_xor(q0,4); q0 += __shfl_xor(q0,8);
      q1 += __shfl_xor(q1,1); q1 += __shfl_xor(q1,2); q1 += __shfl_xor(q1,4); q1 += __shfl_xor(q1,8);
      if (ok && l16 == 0){
        as1[row*4 + head0]     = p0;
        as1[row*4 + head0 + 1] = p1;
        ad1[row*4 + head0]     = q0;
        ad1[row*4 + head0 + 1] = q1;
      }
    }
  }
}

// ---------------- Aggregation 1 (f16 h1 gather, exp-sharing, f16 h1a out) ----------------
// One wave per node; 4 edge-subgroups x 16 lanes; lane holds 8 f16 channels (uint4/edge).
// In the 4-edge unroll each lane computes ONE exp (edge = cl&3, own head); p's shared via shfl.
__global__ __launch_bounds__(256) void agg1_kernel(const unsigned int* __restrict__ h1b,
    const float* __restrict__ a_s1, const float* __restrict__ a_d1,
    const int* __restrict__ offs, const int* __restrict__ csr,
    const float* __restrict__ b1, uint4* __restrict__ h1a4, int N){
  int n = blockIdx.x*4 + (threadIdx.x >> 6);
  if (n >= N) return;
  const int lane = threadIdx.x & 63;
  const int sub  = lane >> 4;       // edge subgroup 0..3
  const int cl   = lane & 15;       // channel-lane
  const int head = cl >> 2;
  const int j    = cl & 3;          // which unrolled edge this lane exps
  const int pbase = (lane & ~15) + (head << 2);
  const float ad = a_d1[n*4+head];
  const int cw = 4*cl;
  float a0=0,a1=0,a2=0,a3=0,a4=0,a5=0,a6=0,a7=0,den=0;
  if (sub == 0){ // self loop
    float p = __expf(leaky(a_s1[n*4+head] + ad));
    uint4 u = *(const uint4*)(h1b + (size_t)n*64 + cw);
    a0 = p*hlo(u.x); a1 = p*hhi(u.x); a2 = p*hlo(u.y); a3 = p*hhi(u.y);
    a4 = p*hlo(u.z); a5 = p*hhi(u.z); a6 = p*hlo(u.w); a7 = p*hhi(u.w);
    den = p;
  }
  const int beg = offs[n], end = offs[n+1];
  int e = beg + sub;
  for (; e + 12 < end; e += 16){
    int s0 = csr[e], s1 = csr[e+4], s2 = csr[e+8], s3 = csr[e+12];
    int sown = j == 0 ? s0 : (j == 1 ? s1 : (j == 2 ? s2 : s3));
    float pown = __expf(leaky(a_s1[sown*4+head] + ad));
    float p0 = __shfl(pown, pbase+0);
    float p1 = __shfl(pown, pbase+1);
    float p2 = __shfl(pown, pbase+2);
    float p3 = __shfl(pown, pbase+3);
    uint4 u0 = *(const uint4*)(h1b + (size_t)s0*64 + cw);
    uint4 u1 = *(const uint4*)(h1b + (size_t)s1*64 + cw);
    uint4 u2 = *(const uint4*)(h1b + (size_t)s2*64 + cw);
    uint4 u3 = *(const uint4*)(h1b + (size_t)s3*64 + cw);
    a0 += p0*hlo(u0.x) + p1*hlo(u1.x) + p2*hlo(u2.x) + p3*hlo(u3.x);
    a1 += p0*hhi(u0.x) + p1*hhi(u1.x) + p2*hhi(u2.x) + p3*hhi(u3.x);
    a2 += p0*hlo(u0.y) + p1*hlo(u1.y) + p2*hlo(u2.y) + p3*hlo(u3.y);
    a3 += p0*hhi(u0.y) + p1*hhi(u1.y) + p2*hhi(u2.y) + p3*hhi(u3.y);
    a4 += p0*hlo(u0.z) + p1*hlo(u1.z) + p2*hlo(u2.z) + p3*hlo(u3.z);
    a5 += p0*hhi(u0.z) + p1*hhi(u1.z) + p2*hhi(u2.z) + p3*hhi(u3.z);
    a6 += p0*hlo(u0.w) + p1*hlo(u1.w) + p2*hlo(u2.w) + p3*hlo(u3.w);
    a7 += p0*hhi(u0.w) + p1*hhi(u1.w) + p2*hhi(u2.w) + p3*hhi(u3.w);
    den += p0 + p1 + p2 + p3;
  }
  for (; e < end; e += 4){
    int s = csr[e];
    float p = __expf(leaky(a_s1[s*4+head] + ad));
    uint4 u = *(const uint4*)(h1b + (size_t)s*64 + cw);
    a0 += p*hlo(u.x); a1 += p*hhi(u.x); a2 += p*hlo(u.y); a3 += p*hhi(u.y);
    a4 += p*hlo(u.z); a5 += p*hhi(u.z); a6 += p*hlo(u.w); a7 += p*hhi(u.w);
    den += p;
  }
  #pragma unroll
  for (int off = 16; off < 64; off <<= 1){
    a0 += __shfl_xor(a0,off); a1 += __shfl_xor(a1,off);
    a2 += __shfl_xor(a2,off); a3 += __shfl_xor(a3,off);
    a4 += __shfl_xor(a4,off); a5 += __shfl_xor(a5,off);
    a6 += __shfl_xor(a6,off); a7 += __shfl_xor(a7,off);
    den += __shfl_xor(den,off);
  }
  if (sub == 0){
    float inv = 1.f/den;
    int ch = 8*cl;
    float4 b0 = *(const float4*)(b1 + ch);
    float4 b4 = *(const float4*)(b1 + ch + 4);
    uint4 w;
    w.x = pack2(f2h(elu(a0*inv+b0.x)), f2h(elu(a1*inv+b0.y)));
    w.y = pack2(f2h(elu(a2*inv+b0.z)), f2h(elu(a3*inv+b0.w)));
    w.z = pack2(f2h(elu(a4*inv+b4.x)), f2h(elu(a5*inv+b4.y)));
    w.w = pack2(f2h(elu(a6*inv+b4.z)), f2h(elu(a7*inv+b4.w)));
    h1a4[(size_t)n*16 + cl] = w;
  }
}

// ---------------- GEMM2: h2(f16) = h1a(f16) @ W2, fused att coefficients ----------------
__global__ __launch_bounds__(256) void gemm2_kernel(const uint4* __restrict__ h1a4, const float* __restrict__ W2,
    const float* __restrict__ att_src, const float* __restrict__ att_dst,
    unsigned int* __restrict__ h2b, float* __restrict__ as2, float* __restrict__ ad2, int M){
  __shared__ float As[64*132];
  __shared__ float Ws[128*32];
  const int tid = threadIdx.x;
  const int cg = tid & 15;
  const int rg = tid >> 4;
  const int m0 = blockIdx.x*64;
  #pragma unroll
  for (int p = 0; p < 4; ++p){
    int jj = tid + 256*p;       // 0..1023
    int r = jj >> 4, q = jj & 15;
    int row = m0 + r;
    uint4 u = make_uint4(0,0,0,0);
    if (row < M) u = h1a4[(size_t)row*16 + q];
    float4 f0 = make_float4(hlo(u.x), hhi(u.x), hlo(u.y), hhi(u.y));
    float4 f1 = make_float4(hlo(u.z), hhi(u.z), hlo(u.w), hhi(u.w));
    *(float4*)&As[r*132 + 8*q]     = f0;
    *(float4*)&As[r*132 + 8*q + 4] = f1;
  }
  #pragma unroll
  for (int p = 0; p < 4; ++p){
    int i = tid + 256*p;
    ((float4*)Ws)[i] = ((const float4*)W2)[i];
  }
  __syncthreads();
  float acc[4][2] = {};
  const float* a0p = &As[(4*rg+0)*132];
  const float* a1p = &As[(4*rg+1)*132];
  const float* a2p = &As[(4*rg+2)*132];
  const float* a3p = &As[(4*rg+3)*132];
  #pragma unroll 8
  for (int kk = 0; kk < 128; ++kk){
    float2 w = *(const float2*)&Ws[kk*32 + 2*cg];
    float a0 = a0p[kk], a1 = a1p[kk], a2 = a2p[kk], a3 = a3p[kk];
    acc[0][0]+=a0*w.x; acc[0][1]+=a0*w.y;
    acc[1][0]+=a1*w.x; acc[1][1]+=a1*w.y;
    acc[2][0]+=a2*w.x; acc[2][1]+=a2*w.y;
    acc[3][0]+=a3*w.x; acc[3][1]+=a3*w.y;
  }
  const float2 sv = *(const float2*)(att_src + 2*cg);
  const float2 dv = *(const float2*)(att_dst + 2*cg);
  #pragma unroll
  for (int i = 0; i < 4; ++i){
    int row = m0 + 4*rg + i;
    if (row < M){
      float2 o = make_float2(acc[i][0], acc[i][1]);
      h2b[(size_t)row*16 + cg] = pack2(f2h(o.x), f2h(o.y));
      float ps = o.x*sv.x + o.y*sv.y;
      float pd = o.x*dv.x + o.y*dv.y;
      ps += __shfl_xor(ps,1); ps += __shfl_xor(ps,2); ps += __shfl_xor(ps,4); ps += __shfl_xor(ps,8);
      pd += __shfl_xor(pd,1); pd += __shfl_xor(pd,2); pd += __shfl_xor(pd,4); pd += __shfl_xor(pd,8);
      if (cg == 0){ as2[row] = ps; ad2[row] = pd; }
    }
  }
}

// ---------------- Aggregation 2 + bias + elu + final linear (f16 h2 gather, exp-sharing) ----------------
__global__ __launch_bounds__(256) void agg2_kernel(const unsigned int* __restrict__ h2b,
    const float* __restrict__ as2, const float* __restrict__ ad2,
    const int* __restrict__ offs, const int* __restrict__ csr,
    const float* __restrict__ b2, const float* __restrict__ linw, const float* __restrict__ linb,
    float* __restrict__ out, int N){
  int n = blockIdx.x*4 + (threadIdx.x >> 6);
  if (n >= N) return;
  const int lane = threadIdx.x & 63;
  const int sub  = lane >> 3;       // edge subgroup 0..7
  const int cl   = lane & 7;        // channel-lane
  const int j    = cl & 3;
  const int pbase = lane & ~7;
  const int cw   = 2*cl;
  const float ad = ad2[n];
  float a0=0,a1=0,a2=0,a3=0,den=0;
  if (sub == 0){
    float p = __expf(leaky(as2[n] + ad));
    uint2 u = *(const uint2*)(h2b + (size_t)n*16 + cw);
    a0 = p*hlo(u.x); a1 = p*hhi(u.x); a2 = p*hlo(u.y); a3 = p*hhi(u.y);
    den = p;
  }
  const int beg = offs[n], end = offs[n+1];
  int e = beg + sub;
  for (; e + 24 < end; e += 32){
    int s0 = csr[e], s1 = csr[e+8], s2 = csr[e+16], s3 = csr[e+24];
    int sown = j == 0 ? s0 : (j == 1 ? s1 : (j == 2 ? s2 : s3));
    float pown = __expf(leaky(as2[sown] + ad));
    float p0 = __shfl(pown, pbase+0);
    float p1 = __shfl(pown, pbase+1);
    float p2 = __shfl(pown, pbase+2);
    float p3 = __shfl(pown, pbase+3);
    uint2 u0 = *(const uint2*)(h2b + (size_t)s0*16 + cw);
    uint2 u1 = *(const uint2*)(h2b + (size_t)s1*16 + cw);
    uint2 u2 = *(const uint2*)(h2b + (size_t)s2*16 + cw);
    uint2 u3 = *(const uint2*)(h2b + (size_t)s3*16 + cw);
    a0 += p0*hlo(u0.x) + p1*hlo(u1.x) + p2*hlo(u2.x) + p3*hlo(u3.x);
    a1 += p0*hhi(u0.x) + p1*hhi(u1.x) + p2*hhi(u2.x) + p3*hhi(u3.x);
    a2 += p0*hlo(u0.y) + p1*hlo(u1.y) + p2*hlo(u2.y) + p3*hlo(u3.y);
    a3 += p0*hhi(u0.y) + p1*hhi(u1.y) + p2*hhi(u2.y) + p3*hhi(u3.y);
    den += p0 + p1 + p2 + p3;
  }
  for (; e < end; e += 8){
    int s = csr[e];
    float p = __expf(leaky(as2[s] + ad));
    uint2 u = *(const uint2*)(h2b + (size_t)s*16 + cw);
    a0 += p*hlo(u.x); a1 += p*hhi(u.x); a2 += p*hlo(u.y); a3 += p*hhi(u.y);
    den += p;
  }
  #pragma unroll
  for (int off = 8; off < 64; off <<= 1){
    a0 += __shfl_xor(a0,off); a1 += __shfl_xor(a1,off);
    a2 += __shfl_xor(a2,off); a3 += __shfl_xor(a3,off);
    den += __shfl_xor(den,off);
  }
  float inv = 1.f/den;
  int ch = 4*cl;
  float o0 = elu(a0*inv + b2[ch+0]);
  float o1 = elu(a1*inv + b2[ch+1]);
  float o2 = elu(a2*inv + b2[ch+2]);
  float o3 = elu(a3*inv + b2[ch+3]);
  float r0 = o0*linw[2*(ch+0)]   + o1*linw[2*(ch+1)]   + o2*linw[2*(ch+2)]   + o3*linw[2*(ch+3)];
  float r1 = o0*linw[2*(ch+0)+1] + o1*linw[2*(ch+1)+1] + o2*linw[2*(ch+2)+1] + o3*linw[2*(ch+3)+1];
  r0 += __shfl_xor(r0,1); r0 += __shfl_xor(r0,2); r0 += __shfl_xor(r0,4);
  r1 += __shfl_xor(r1,1); r1 += __shfl_xor(r1,2); r1 += __shfl_xor(r1,4);
  if (lane == 0){
    out[(size_t)n*2+0] = r0 + linb[0];
    out[(size_t)n*2+1] = r1 + linb[1];
  }
}

// ---------------- launch ----------------
extern "C" void kernel_launch(void* const* d_in, const int* in_sizes, int n_in,
                              void* d_out, int out_size, void* d_ws, size_t ws_size,
                              hipStream_t stream) {
  const float* x    = (const float*)d_in[0];
  const int*   ei   = (const int*)  d_in[1];
  const float* W1   = (const float*)d_in[2];
  const float* as1w = (const float*)d_in[3];
  const float* ad1w = (const float*)d_in[4];
  const float* b1   = (const float*)d_in[5];
  const float* W2   = (const float*)d_in[6];
  const float* as2w = (const float*)d_in[7];
  const float* ad2w = (const float*)d_in[8];
  const float* b2   = (const float*)d_in[9];
  const float* linw = (const float*)d_in[10];
  const float* linb = (const float*)d_in[11];
  float* out = (float*)d_out;

  const int N = in_sizes[0] / IN_DIM;   // 50000
  const int E = in_sizes[1] / 2;        // 800000

  const int NBUK = (N + 511) >> BSHIFT;           // 98
  const int NCHK = (E + 2047) / 2048;             // 391
  const int CSTR = (NCHK + 3) & ~3;               // padded stride

  char* ws = (char*)d_ws;
  auto alloc = [&](size_t bytes) -> char* {
    char* p = ws; ws += (bytes + 255) & ~(size_t)255; return p;
  };
  unsigned short* h1b = (unsigned short*)alloc((size_t)N*F1*2);  // f16; also hosts im during sort
  uint4* h1a4 = (uint4*)alloc((size_t)N*F1*2);                   // f16 packed
  unsigned int* h2b = (unsigned int*)alloc((size_t)N*HID*2);     // f16 packed
  float* a_s1 = (float*)alloc((size_t)N*4*4);
  float* a_d1 = (float*)alloc((size_t)N*4*4);
  float* a_s2 = (float*)alloc((size_t)N*4);
  float* a_d2 = (float*)alloc((size_t)N*4);
  size_t cntblk_bytes = (size_t)NBUK*CSTR*4;
  if (cntblk_bytes < 131072) cntblk_bytes = 131072;
  int* cnt_blk = (int*)alloc(cntblk_bytes);        // also hosts W1h/W1l after passB
  int* btot    = (int*)alloc((size_t)(NBUK+1)*4);
  int* bbase   = (int*)alloc((size_t)(NBUK+1)*4);
  int* offs    = (int*)alloc((size_t)(N+1)*4);
  int* csr     = (int*)alloc((size_t)E*4);
  // aliases (lifetimes disjoint by kernel ordering on the stream):
  unsigned int* im = (unsigned int*)h1b;           // sort intermediate, dead before gemm1 writes h1b
  unsigned short* W1h = (unsigned short*)cnt_blk;  // cnt_blk dead after bukscat
  unsigned short* W1l = W1h + (size_t)IN_DIM*F1;

  const int* srcs = ei;       // edge_index[0]
  const int* dsts = ei + E;   // edge_index[1]

  bukcnt_kernel<<<NCHK, 256, 0, stream>>>(dsts, cnt_blk, E, NBUK, CSTR);
  bukscan1_kernel<<<NBUK, 256, 0, stream>>>(cnt_blk, btot, NCHK, CSTR);
  bukscan2_kernel<<<1, 256, 0, stream>>>(btot, bbase, offs, NBUK, N, E);
  bukscat_kernel<<<NCHK, 256, 0, stream>>>(srcs, dsts, cnt_blk, bbase, im, E, NBUK, CSTR);
  bukfine_kernel<<<NBUK, 256, 0, stream>>>(im, bbase, offs, csr, N);
  convw_kernel<<<(IN_DIM*F1)/256, 256, 0, stream>>>(W1, W1h, W1l);
  gemm1_kernel<<<(N+63)/64, 256, 0, stream>>>(x, W1h, W1l, as1w, ad1w, h1b, a_s1, a_d1, N);
  agg1_kernel<<<(N+3)/4, 256, 0, stream>>>((const unsigned int*)h1b, a_s1, a_d1, offs, csr, b1, h1a4, N);
  gemm2_kernel<<<(N+63)/64, 256, 0, stream>>>(h1a4, W2, as2w, ad2w, h2b, a_s2, a_d2, N);
  agg2_kernel<<<(N+3)/4, 256, 0, stream>>>(h2b, a_s2, a_d2, offs, csr, b2, linw, linb, out, N);
}

// Round 9
// 232.987 us; speedup vs baseline: 1.0474x; 1.0419x over previous
//
#include <hip/hip_runtime.h>
#include <hip/hip_fp16.h>

#define IN_DIM 256
#define HID 32
#define HEADS 4
#define F1 128   // HEADS*HID
#define BSHIFT 9           // 512 nodes per coarse bucket
#define MAXBUK 128         // LDS sizing (actual nbuk = 98 for N=50000)

static __device__ __forceinline__ float leaky(float x){ return x > 0.f ? x : 0.2f*x; }
static __device__ __forceinline__ float elu(float x){ return x > 0.f ? x : (__expf(x) - 1.f); }

// bf16 helpers (round-to-nearest-even) — used for the GEMM1 MFMA split
static __device__ __forceinline__ unsigned short f2bf(float f){
  unsigned int u = __float_as_uint(f);
  u += 0x7FFFu + ((u >> 16) & 1u);
  return (unsigned short)(u >> 16);
}
static __device__ __forceinline__ float bf2f(unsigned short h){
  return __uint_as_float(((unsigned int)h) << 16);
}
static __device__ __forceinline__ unsigned int pack2(unsigned short a, unsigned short b){
  return (unsigned int)a | ((unsigned int)b << 16);
}
// f16 helpers — activation storage
static __device__ __forceinline__ unsigned short f2h(float f){
  return __half_as_ushort(__float2half(f));
}
static __device__ __forceinline__ float hlo(unsigned int u){
  return __half2float(__ushort_as_half((unsigned short)(u & 0xFFFFu)));
}
static __device__ __forceinline__ float hhi(unsigned int u){
  return __half2float(__ushort_as_half((unsigned short)(u >> 16)));
}

__device__ __forceinline__ int block_excl_scan(int v, int tid, int* total){
  __shared__ int ws[8];
  int lane = tid & 63, w = tid >> 6;
  int incl = v;
  #pragma unroll
  for (int d = 1; d < 64; d <<= 1){ int o = __shfl_up(incl, d); if (lane >= d) incl += o; }
  if (lane == 63) ws[w] = incl;
  __syncthreads();
  if (tid == 0){ int s = 0; for (int i = 0; i < 4; ++i){ int t = ws[i]; ws[i] = s; s += t; } ws[4] = s; }
  __syncthreads();
  *total = ws[4];
  int e = ws[w] + incl - v;   // exclusive
  __syncthreads();            // allow reuse of ws in loops
  return e;
}

// ---------------- CSR build: deterministic two-level bucket sort ----------------
// bukcnt also carries the W1 f32->bf16 hi/lo transpose (convw fold: 1 less launch)
__global__ __launch_bounds__(256) void bukcnt_kernel(const int* __restrict__ dsts,
    int* __restrict__ cnt_blk, const float* __restrict__ W1,
    unsigned short* __restrict__ Wh, unsigned short* __restrict__ Wl,
    int E, int nbuk, int stride){
  __shared__ int lcnt[MAXBUK];
  int tid = threadIdx.x, blk = blockIdx.x;
  int gid = blk*256 + tid;
  if (gid < IN_DIM*F1){           // folded convw: i = n*256 + k
    int n = gid >> 8, k = gid & 255;
    float w = W1[(size_t)k*F1 + n];
    unsigned short h = f2bf(w);
    Wh[gid] = h;
    Wl[gid] = f2bf(w - bf2f(h));
  }
  if (tid < nbuk) lcnt[tid] = 0;
  __syncthreads();
  int base = blk*2048;
  #pragma unroll
  for (int j = 0; j < 8; ++j){
    int i = base + tid + j*256;
    if (i < E) atomicAdd(&lcnt[dsts[i] >> BSHIFT], 1);
  }
  __syncthreads();
  if (tid < nbuk) cnt_blk[tid*stride + blk] = lcnt[tid];
}

__global__ __launch_bounds__(256) void bukscan1_kernel(int* __restrict__ cnt_blk,
    int* __restrict__ btot, int nchk, int stride){
  int b = blockIdx.x, tid = threadIdx.x;
  int carry = 0;
  for (int s = 0; s < nchk; s += 256){
    int i = s + tid;
    int v = (i < nchk) ? cnt_blk[b*stride + i] : 0;
    int tot; int e = block_excl_scan(v, tid, &tot);
    if (i < nchk) cnt_blk[b*stride + i] = carry + e;
    carry += tot;
  }
  if (tid == 0) btot[b] = carry;
}

__global__ __launch_bounds__(256) void bukscan2_kernel(const int* __restrict__ btot,
    int* __restrict__ bucket_base, int* __restrict__ offs, int nbuk, int Nn, int E){
  int tid = threadIdx.x;
  int v = (tid < nbuk) ? btot[tid] : 0;
  int tot; int e = block_excl_scan(v, tid, &tot);
  if (tid <= nbuk) bucket_base[tid] = e;
  if (tid == 0) offs[Nn] = E;
}

// passB: scatter packed (src | localdst<<16); relies on N < 65536, 512-node buckets
__global__ __launch_bounds__(256) void bukscat_kernel(const int* __restrict__ srcs,
    const int* __restrict__ dsts, const int* __restrict__ cnt_blk,
    const int* __restrict__ bucket_base, unsigned int* __restrict__ im,
    int E, int nbuk, int stride){
  __shared__ int lcur[MAXBUK];
  int tid = threadIdx.x, blk = blockIdx.x;
  if (tid < nbuk) lcur[tid] = bucket_base[tid] + cnt_blk[tid*stride + blk];
  __syncthreads();
  int base = blk*2048;
  #pragma unroll
  for (int j = 0; j < 8; ++j){
    int i = base + tid + j*256;
    if (i < E){
      int s = srcs[i], d = dsts[i];
      int r = atomicAdd(&lcur[d >> BSHIFT], 1);
      im[r] = (unsigned)s | (((unsigned)d & 511u) << 16);
    }
  }
}

// passC: per-bucket fine sort (all LDS); csr window contiguous per bucket
__global__ __launch_bounds__(256) void bukfine_kernel(const unsigned int* __restrict__ im,
    const int* __restrict__ bucket_base, int* __restrict__ offs, int* __restrict__ csr, int Nn){
  __shared__ int lcnt[512], lpfx[512];
  int b = blockIdx.x, tid = threadIdx.x;
  int node0 = b << BSHIFT;
  int nn = min(512, Nn - node0);
  lcnt[tid] = 0; lcnt[tid+256] = 0;
  __syncthreads();
  int ebeg = bucket_base[b], eend = bucket_base[b+1];
  for (int i = ebeg + tid; i < eend; i += 256)
    atomicAdd(&lcnt[im[i] >> 16], 1);
  __syncthreads();
  int carry = 0;
  for (int s = 0; s < 512; s += 256){
    int v = lcnt[s + tid];
    int tot; int e = block_excl_scan(v, tid, &tot);
    lpfx[s + tid] = carry + e;
    carry += tot;
  }
  __syncthreads();
  if (tid < nn) offs[node0 + tid] = ebeg + lpfx[tid];
  if (tid + 256 < nn) offs[node0 + tid + 256] = ebeg + lpfx[tid + 256];
  lcnt[tid] = ebeg + lpfx[tid];
  lcnt[tid+256] = ebeg + lpfx[tid+256];
  __syncthreads();
  for (int i = ebeg + tid; i < eend; i += 256){
    unsigned int u = im[i];
    int pos = atomicAdd(&lcnt[u >> 16], 1);
    csr[pos] = (int)(u & 0xFFFFu);
  }
}

// ---------------- GEMM1 (MFMA bf16 split): h1(f16) = x @ W1, fused att coefficients ----------------
typedef __attribute__((ext_vector_type(8))) short bf8_t;
typedef __attribute__((ext_vector_type(4))) float f4_t;
typedef _Float16 f16x8 __attribute__((ext_vector_type(8)));

__global__ __launch_bounds__(256) void gemm1_kernel(const float* __restrict__ x,
    const unsigned short* __restrict__ Wh, const unsigned short* __restrict__ Wl,
    const float* __restrict__ att_src, const float* __restrict__ att_dst,
    unsigned short* __restrict__ h1b, float* __restrict__ as1, float* __restrict__ ad1, int M){
  __shared__ uint4 AhV[64][5], AlV[64][5];    // [row][k-chunk], 80B rows (2-way only = free)
  __shared__ uint4 BhV[128][5], BlV[128][5];  // [n][k-chunk]
  const int tid = threadIdx.x;
  const int m0 = blockIdx.x*64;
  const int wave = tid >> 6, lane = tid & 63;
  const int quad = lane >> 4, l16 = lane & 15;
  const int wr = (wave & 1)*32;
  const int wc = (wave >> 1)*64;
  f4_t acc[2][4];
  #pragma unroll
  for (int r = 0; r < 2; ++r)
    #pragma unroll
    for (int c = 0; c < 4; ++c)
      #pragma unroll
      for (int i = 0; i < 4; ++i) acc[r][c][i] = 0.f;

  const int ar = tid >> 2, akc = tid & 3;
  const bool aok = (m0 + ar) < M;
  const float* ap = x + (size_t)(m0 + ar)*IN_DIM + 8*akc;
  const int bn = tid >> 1, bkc = (tid & 1)*2;
  const unsigned short* bph = Wh + (size_t)bn*256 + 16*(tid & 1);
  const unsigned short* bpl = Wl + (size_t)bn*256 + 16*(tid & 1);

  for (int k0 = 0; k0 < IN_DIM; k0 += 32){
    float4 a0 = make_float4(0.f,0.f,0.f,0.f), a1 = a0;
    if (aok){ a0 = *(const float4*)(ap + k0); a1 = *(const float4*)(ap + k0 + 4); }
    float v[8] = {a0.x,a0.y,a0.z,a0.w,a1.x,a1.y,a1.z,a1.w};
    unsigned short hh[8], ll[8];
    #pragma unroll
    for (int j = 0; j < 8; ++j){
      unsigned short h = f2bf(v[j]); hh[j] = h; ll[j] = f2bf(v[j] - bf2f(h));
    }
    uint4 hv; hv.x = pack2(hh[0],hh[1]); hv.y = pack2(hh[2],hh[3]); hv.z = pack2(hh[4],hh[5]); hv.w = pack2(hh[6],hh[7]);
    uint4 lv; lv.x = pack2(ll[0],ll[1]); lv.y = pack2(ll[2],ll[3]); lv.z = pack2(ll[4],ll[5]); lv.w = pack2(ll[6],ll[7]);
    AhV[ar][akc] = hv;
    AlV[ar][akc] = lv;
    BhV[bn][bkc+0] = *(const uint4*)(bph + k0);
    BhV[bn][bkc+1] = *(const uint4*)(bph + k0 + 8);
    BlV[bn][bkc+0] = *(const uint4*)(bpl + k0);
    BlV[bn][bkc+1] = *(const uint4*)(bpl + k0 + 8);
    __syncthreads();

    bf8_t arh[2], arl[2], brh[4], brl[4];
    #pragma unroll
    for (int r = 0; r < 2; ++r){
      arh[r] = *(const bf8_t*)&AhV[wr + r*16 + l16][quad];
      arl[r] = *(const bf8_t*)&AlV[wr + r*16 + l16][quad];
    }
    #pragma unroll
    for (int c = 0; c < 4; ++c){
      brh[c] = *(const bf8_t*)&BhV[wc + c*16 + l16][quad];
      brl[c] = *(const bf8_t*)&BlV[wc + c*16 + l16][quad];
    }
    #pragma unroll
    for (int r = 0; r < 2; ++r)
      #pragma unroll
      for (int c = 0; c < 4; ++c){
        acc[r][c] = __builtin_amdgcn_mfma_f32_16x16x32_bf16(arh[r], brh[c], acc[r][c], 0, 0, 0);
        acc[r][c] = __builtin_amdgcn_mfma_f32_16x16x32_bf16(arh[r], brl[c], acc[r][c], 0, 0, 0);
        acc[r][c] = __builtin_amdgcn_mfma_f32_16x16x32_bf16(arl[r], brh[c], acc[r][c], 0, 0, 0);
      }
    __syncthreads();
  }

  const int head0 = wc >> 5;
  float sv[4], dv[4];
  #pragma unroll
  for (int c = 0; c < 4; ++c){
    int col_in_head = (c & 1)*16 + l16;
    sv[c] = att_src[(head0 + (c >> 1))*HID + col_in_head];
    dv[c] = att_dst[(head0 + (c >> 1))*HID + col_in_head];
  }
  #pragma unroll
  for (int r = 0; r < 2; ++r){
    #pragma unroll
    for (int i = 0; i < 4; ++i){
      int row = m0 + wr + r*16 + quad*4 + i;
      bool ok = row < M;
      float hv0 = acc[r][0][i], hv1 = acc[r][1][i], hv2 = acc[r][2][i], hv3 = acc[r][3][i];
      if (ok){
        unsigned short* hp = h1b + (size_t)row*F1 + wc + l16;
        hp[0]  = f2h(hv0); hp[16] = f2h(hv1); hp[32] = f2h(hv2); hp[48] = f2h(hv3);
      }
      float p0 = hv0*sv[0] + hv1*sv[1];
      float p1 = hv2*sv[2] + hv3*sv[3];
      float q0 = hv0*dv[0] + hv1*dv[1];
      float q1 = hv2*dv[2] + hv3*dv[3];
      p0 += __shfl_xor(p0,1); p0 += __shfl_xor(p0,2); p0 += __shfl_xor(p0,4); p0 += __shfl_xor(p0,8);
      p1 += __shfl_xor(p1,1); p1 += __shfl_xor(p1,2); p1 += __shfl_xor(p1,4); p1 += __shfl_xor(p1,8);
      q0 += __shfl_xor(q0,1); q0 += __shfl_xor(q0,2); q0 += __shfl_xor(q0,4); q0 += __shfl_xor(q0,8);
      q1 += __shfl_xor(q1,1); q1 += __shfl_xor(q1,2); q1 += __shfl_xor(q1,4); q1 += __shfl_xor(q1,8);
      if (ok && l16 == 0){
        as1[row*4 + head0]     = p0;
        as1[row*4 + head0 + 1] = p1;
        ad1[row*4 + head0]     = q0;
        ad1[row*4 + head0 + 1] = q1;
      }
    }
  }
}

// ---------------- Aggregation 1 (f16 h1 gather, exp-sharing, f16 h1a out) ----------------
__global__ __launch_bounds__(256) void agg1_kernel(const unsigned int* __restrict__ h1b,
    const float* __restrict__ a_s1, const float* __restrict__ a_d1,
    const int* __restrict__ offs, const int* __restrict__ csr,
    const float* __restrict__ b1, uint4* __restrict__ h1a4, int N){
  int n = blockIdx.x*4 + (threadIdx.x >> 6);
  if (n >= N) return;
  const int lane = threadIdx.x & 63;
  const int sub  = lane >> 4;       // edge subgroup 0..3
  const int cl   = lane & 15;       // channel-lane
  const int head = cl >> 2;
  const int j    = cl & 3;          // which unrolled edge this lane exps
  const int pbase = (lane & ~15) + (head << 2);
  const float ad = a_d1[n*4+head];
  const int cw = 4*cl;
  float a0=0,a1=0,a2=0,a3=0,a4=0,a5=0,a6=0,a7=0,den=0;
  if (sub == 0){ // self loop
    float p = __expf(leaky(a_s1[n*4+head] + ad));
    uint4 u = *(const uint4*)(h1b + (size_t)n*64 + cw);
    a0 = p*hlo(u.x); a1 = p*hhi(u.x); a2 = p*hlo(u.y); a3 = p*hhi(u.y);
    a4 = p*hlo(u.z); a5 = p*hhi(u.z); a6 = p*hlo(u.w); a7 = p*hhi(u.w);
    den = p;
  }
  const int beg = offs[n], end = offs[n+1];
  int e = beg + sub;
  for (; e + 12 < end; e += 16){
    int s0 = csr[e], s1 = csr[e+4], s2 = csr[e+8], s3 = csr[e+12];
    int sown = j == 0 ? s0 : (j == 1 ? s1 : (j == 2 ? s2 : s3));
    float pown = __expf(leaky(a_s1[sown*4+head] + ad));
    float p0 = __shfl(pown, pbase+0);
    float p1 = __shfl(pown, pbase+1);
    float p2 = __shfl(pown, pbase+2);
    float p3 = __shfl(pown, pbase+3);
    uint4 u0 = *(const uint4*)(h1b + (size_t)s0*64 + cw);
    uint4 u1 = *(const uint4*)(h1b + (size_t)s1*64 + cw);
    uint4 u2 = *(const uint4*)(h1b + (size_t)s2*64 + cw);
    uint4 u3 = *(const uint4*)(h1b + (size_t)s3*64 + cw);
    a0 += p0*hlo(u0.x) + p1*hlo(u1.x) + p2*hlo(u2.x) + p3*hlo(u3.x);
    a1 += p0*hhi(u0.x) + p1*hhi(u1.x) + p2*hhi(u2.x) + p3*hhi(u3.x);
    a2 += p0*hlo(u0.y) + p1*hlo(u1.y) + p2*hlo(u2.y) + p3*hlo(u3.y);
    a3 += p0*hhi(u0.y) + p1*hhi(u1.y) + p2*hhi(u2.y) + p3*hhi(u3.y);
    a4 += p0*hlo(u0.z) + p1*hlo(u1.z) + p2*hlo(u2.z) + p3*hlo(u3.z);
    a5 += p0*hhi(u0.z) + p1*hhi(u1.z) + p2*hhi(u2.z) + p3*hhi(u3.z);
    a6 += p0*hlo(u0.w) + p1*hlo(u1.w) + p2*hlo(u2.w) + p3*hlo(u3.w);
    a7 += p0*hhi(u0.w) + p1*hhi(u1.w) + p2*hhi(u2.w) + p3*hhi(u3.w);
    den += p0 + p1 + p2 + p3;
  }
  for (; e < end; e += 4){
    int s = csr[e];
    float p = __expf(leaky(a_s1[s*4+head] + ad));
    uint4 u = *(const uint4*)(h1b + (size_t)s*64 + cw);
    a0 += p*hlo(u.x); a1 += p*hhi(u.x); a2 += p*hlo(u.y); a3 += p*hhi(u.y);
    a4 += p*hlo(u.z); a5 += p*hhi(u.z); a6 += p*hlo(u.w); a7 += p*hhi(u.w);
    den += p;
  }
  #pragma unroll
  for (int off = 16; off < 64; off <<= 1){
    a0 += __shfl_xor(a0,off); a1 += __shfl_xor(a1,off);
    a2 += __shfl_xor(a2,off); a3 += __shfl_xor(a3,off);
    a4 += __shfl_xor(a4,off); a5 += __shfl_xor(a5,off);
    a6 += __shfl_xor(a6,off); a7 += __shfl_xor(a7,off);
    den += __shfl_xor(den,off);
  }
  if (sub == 0){
    float inv = 1.f/den;
    int ch = 8*cl;
    float4 b0 = *(const float4*)(b1 + ch);
    float4 b4 = *(const float4*)(b1 + ch + 4);
    uint4 w;
    w.x = pack2(f2h(elu(a0*inv+b0.x)), f2h(elu(a1*inv+b0.y)));
    w.y = pack2(f2h(elu(a2*inv+b0.z)), f2h(elu(a3*inv+b0.w)));
    w.z = pack2(f2h(elu(a4*inv+b4.x)), f2h(elu(a5*inv+b4.y)));
    w.w = pack2(f2h(elu(a6*inv+b4.z)), f2h(elu(a7*inv+b4.w)));
    h1a4[(size_t)n*16 + cl] = w;
  }
}

// ---------------- GEMM2 (MFMA f16): h2(f16) = h1a(f16) @ W2, fused att coefficients ----------------
// A = h1a f16 EXACT (staging is a raw copy). B = W2 split: f16 hi + f16 lo*4096 (2 accumulators).
// K=128 in one LDS shot, no k-loop. Block = 64 rows; wave w owns rows 16w..16w+15, cols 0..31.
__global__ __launch_bounds__(256) void gemm2_kernel(const uint4* __restrict__ h1a4, const float* __restrict__ W2,
    const float* __restrict__ att_src, const float* __restrict__ att_dst,
    unsigned short* __restrict__ h2s, float* __restrict__ as2, float* __restrict__ ad2, int M){
  __shared__ unsigned short Ab[64*136];   // [row][k] f16, stride 136 (b128 reads: 4-way = ok)
  __shared__ unsigned short Bh[32*136];   // [n][k] f16 hi
  __shared__ unsigned short Bl[32*136];   // [n][k] f16 lo*4096
  const int tid = threadIdx.x;
  const int m0 = blockIdx.x*64;
  const int wave = tid >> 6, lane = tid & 63;
  const int quad = lane >> 4, l16 = lane & 15;

  // stage A: raw copy of 64 rows x 16 uint4
  #pragma unroll
  for (int p = 0; p < 4; ++p){
    int idx = tid + 256*p;            // 0..1023
    int r = idx >> 4, q = idx & 15;
    int row = m0 + r;
    uint4 u = make_uint4(0,0,0,0);
    if (row < M) u = h1a4[(size_t)row*16 + q];
    *(uint4*)&Ab[r*136 + 8*q] = u;
  }
  // stage B: W2 f32 [k][n] -> f16 hi/lo transposed [n][k]
  {
    const float4* w4 = (const float4*)W2;
    #pragma unroll
    for (int p = 0; p < 4; ++p){
      int idx = tid*4 + p;            // 0..1023 float4s
      float4 v = w4[idx];
      int e0 = idx*4;                 // element index: k = e>>5, n = e&31
      float vv[4] = {v.x, v.y, v.z, v.w};
      #pragma unroll
      for (int t = 0; t < 4; ++t){
        int e = e0 + t, k = e >> 5, n = e & 31;
        __half hi = __float2half(vv[t]);
        __half lo = __float2half((vv[t] - __half2float(hi)) * 4096.f);
        Bh[n*136 + k] = __half_as_ushort(hi);
        Bl[n*136 + k] = __half_as_ushort(lo);
      }
    }
  }
  __syncthreads();

  f4_t acch[2], accl[2];
  #pragma unroll
  for (int c = 0; c < 2; ++c)
    #pragma unroll
    for (int i = 0; i < 4; ++i){ acch[c][i] = 0.f; accl[c][i] = 0.f; }

  #pragma unroll
  for (int kc = 0; kc < 4; ++kc){
    f16x8 a = *(const f16x8*)&Ab[(16*wave + l16)*136 + kc*32 + quad*8];
    #pragma unroll
    for (int c = 0; c < 2; ++c){
      f16x8 bh = *(const f16x8*)&Bh[(16*c + l16)*136 + kc*32 + quad*8];
      f16x8 bl = *(const f16x8*)&Bl[(16*c + l16)*136 + kc*32 + quad*8];
      acch[c] = __builtin_amdgcn_mfma_f32_16x16x32_f16(a, bh, acch[c], 0, 0, 0);
      accl[c] = __builtin_amdgcn_mfma_f32_16x16x32_f16(a, bl, accl[c], 0, 0, 0);
    }
  }

  // epilogue: C/D col = l16 (within tile), row = 16*wave + quad*4 + i
  const float sv0 = att_src[l16],      dv0 = att_dst[l16];
  const float sv1 = att_src[l16 + 16], dv1 = att_dst[l16 + 16];
  #pragma unroll
  for (int i = 0; i < 4; ++i){
    int row = m0 + 16*wave + quad*4 + i;
    bool ok = row < M;
    float v0 = acch[0][i] + accl[0][i] * (1.f/4096.f);
    float v1 = acch[1][i] + accl[1][i] * (1.f/4096.f);
    if (ok){
      h2s[(size_t)row*32 + l16]      = f2h(v0);
      h2s[(size_t)row*32 + l16 + 16] = f2h(v1);
    }
    float ps = v0*sv0 + v1*sv1;
    float pd = v0*dv0 + v1*dv1;
    ps += __shfl_xor(ps,1); ps += __shfl_xor(ps,2); ps += __shfl_xor(ps,4); ps += __shfl_xor(ps,8);
    pd += __shfl_xor(pd,1); pd += __shfl_xor(pd,2); pd += __shfl_xor(pd,4); pd += __shfl_xor(pd,8);
    if (ok && l16 == 0){ as2[row] = ps; ad2[row] = pd; }
  }
}

// ---------------- Aggregation 2 + bias + elu + final linear (f16 h2 gather, exp-sharing) ----------------
__global__ __launch_bounds__(256) void agg2_kernel(const unsigned int* __restrict__ h2b,
    const float* __restrict__ as2, const float* __restrict__ ad2,
    const int* __restrict__ offs, const int* __restrict__ csr,
    const float* __restrict__ b2, const float* __restrict__ linw, const float* __restrict__ linb,
    float* __restrict__ out, int N){
  int n = blockIdx.x*4 + (threadIdx.x >> 6);
  if (n >= N) return;
  const int lane = threadIdx.x & 63;
  const int sub  = lane >> 3;       // edge subgroup 0..7
  const int cl   = lane & 7;        // channel-lane
  const int j    = cl & 3;
  const int pbase = lane & ~7;
  const int cw   = 2*cl;
  const float ad = ad2[n];
  float a0=0,a1=0,a2=0,a3=0,den=0;
  if (sub == 0){
    float p = __expf(leaky(as2[n] + ad));
    uint2 u = *(const uint2*)(h2b + (size_t)n*16 + cw);
    a0 = p*hlo(u.x); a1 = p*hhi(u.x); a2 = p*hlo(u.y); a3 = p*hhi(u.y);
    den = p;
  }
  const int beg = offs[n], end = offs[n+1];
  int e = beg + sub;
  for (; e + 24 < end; e += 32){
    int s0 = csr[e], s1 = csr[e+8], s2 = csr[e+16], s3 = csr[e+24];
    int sown = j == 0 ? s0 : (j == 1 ? s1 : (j == 2 ? s2 : s3));
    float pown = __expf(leaky(as2[sown] + ad));
    float p0 = __shfl(pown, pbase+0);
    float p1 = __shfl(pown, pbase+1);
    float p2 = __shfl(pown, pbase+2);
    float p3 = __shfl(pown, pbase+3);
    uint2 u0 = *(const uint2*)(h2b + (size_t)s0*16 + cw);
    uint2 u1 = *(const uint2*)(h2b + (size_t)s1*16 + cw);
    uint2 u2 = *(const uint2*)(h2b + (size_t)s2*16 + cw);
    uint2 u3 = *(const uint2*)(h2b + (size_t)s3*16 + cw);
    a0 += p0*hlo(u0.x) + p1*hlo(u1.x) + p2*hlo(u2.x) + p3*hlo(u3.x);
    a1 += p0*hhi(u0.x) + p1*hhi(u1.x) + p2*hhi(u2.x) + p3*hhi(u3.x);
    a2 += p0*hlo(u0.y) + p1*hlo(u1.y) + p2*hlo(u2.y) + p3*hlo(u3.y);
    a3 += p0*hhi(u0.y) + p1*hhi(u1.y) + p2*hhi(u2.y) + p3*hhi(u3.y);
    den += p0 + p1 + p2 + p3;
  }
  for (; e < end; e += 8){
    int s = csr[e];
    float p = __expf(leaky(as2[s] + ad));
    uint2 u = *(const uint2*)(h2b + (size_t)s*16 + cw);
    a0 += p*hlo(u.x); a1 += p*hhi(u.x); a2 += p*hlo(u.y); a3 += p*hhi(u.y);
    den += p;
  }
  #pragma unroll
  for (int off = 8; off < 64; off <<= 1){
    a0 += __shfl_xor(a0,off); a1 += __shfl_xor(a1,off);
    a2 += __shfl_xor(a2,off); a3 += __shfl_xor(a3,off);
    den += __shfl_xor(den,off);
  }
  float inv = 1.f/den;
  int ch = 4*cl;
  float o0 = elu(a0*inv + b2[ch+0]);
  float o1 = elu(a1*inv + b2[ch+1]);
  float o2 = elu(a2*inv + b2[ch+2]);
  float o3 = elu(a3*inv + b2[ch+3]);
  float r0 = o0*linw[2*(ch+0)]   + o1*linw[2*(ch+1)]   + o2*linw[2*(ch+2)]   + o3*linw[2*(ch+3)];
  float r1 = o0*linw[2*(ch+0)+1] + o1*linw[2*(ch+1)+1] + o2*linw[2*(ch+2)+1] + o3*linw[2*(ch+3)+1];
  r0 += __shfl_xor(r0,1); r0 += __shfl_xor(r0,2); r0 += __shfl_xor(r0,4);
  r1 += __shfl_xor(r1,1); r1 += __shfl_xor(r1,2); r1 += __shfl_xor(r1,4);
  if (lane == 0){
    out[(size_t)n*2+0] = r0 + linb[0];
    out[(size_t)n*2+1] = r1 + linb[1];
  }
}

// ---------------- launch ----------------
extern "C" void kernel_launch(void* const* d_in, const int* in_sizes, int n_in,
                              void* d_out, int out_size, void* d_ws, size_t ws_size,
                              hipStream_t stream) {
  const float* x    = (const float*)d_in[0];
  const int*   ei   = (const int*)  d_in[1];
  const float* W1   = (const float*)d_in[2];
  const float* as1w = (const float*)d_in[3];
  const float* ad1w = (const float*)d_in[4];
  const float* b1   = (const float*)d_in[5];
  const float* W2   = (const float*)d_in[6];
  const float* as2w = (const float*)d_in[7];
  const float* ad2w = (const float*)d_in[8];
  const float* b2   = (const float*)d_in[9];
  const float* linw = (const float*)d_in[10];
  const float* linb = (const float*)d_in[11];
  float* out = (float*)d_out;

  const int N = in_sizes[0] / IN_DIM;   // 50000
  const int E = in_sizes[1] / 2;        // 800000

  const int NBUK = (N + 511) >> BSHIFT;           // 98
  const int NCHK = (E + 2047) / 2048;             // 391
  const int CSTR = (NCHK + 3) & ~3;               // padded stride

  char* ws = (char*)d_ws;
  auto alloc = [&](size_t bytes) -> char* {
    char* p = ws; ws += (bytes + 255) & ~(size_t)255; return p;
  };
  // ws_size is 256 MiB (observed) — no aliasing needed; everything gets its own region.
  unsigned short* h1b = (unsigned short*)alloc((size_t)N*F1*2);  // f16
  uint4* h1a4 = (uint4*)alloc((size_t)N*F1*2);                   // f16 packed
  unsigned short* h2s = (unsigned short*)alloc((size_t)N*HID*2); // f16
  float* a_s1 = (float*)alloc((size_t)N*4*4);
  float* a_d1 = (float*)alloc((size_t)N*4*4);
  float* a_s2 = (float*)alloc((size_t)N*4);
  float* a_d2 = (float*)alloc((size_t)N*4);
  int* cnt_blk = (int*)alloc((size_t)NBUK*CSTR*4);
  int* btot    = (int*)alloc((size_t)(NBUK+1)*4);
  int* bbase   = (int*)alloc((size_t)(NBUK+1)*4);
  int* offs    = (int*)alloc((size_t)(N+1)*4);
  int* csr     = (int*)alloc((size_t)E*4);
  unsigned int* im = (unsigned int*)alloc((size_t)E*4);
  unsigned short* W1h = (unsigned short*)alloc((size_t)IN_DIM*F1*2);
  unsigned short* W1l = (unsigned short*)alloc((size_t)IN_DIM*F1*2);

  const int* srcs = ei;       // edge_index[0]
  const int* dsts = ei + E;   // edge_index[1]

  bukcnt_kernel<<<NCHK, 256, 0, stream>>>(dsts, cnt_blk, W1, W1h, W1l, E, NBUK, CSTR);
  bukscan1_kernel<<<NBUK, 256, 0, stream>>>(cnt_blk, btot, NCHK, CSTR);
  bukscan2_kernel<<<1, 256, 0, stream>>>(btot, bbase, offs, NBUK, N, E);
  bukscat_kernel<<<NCHK, 256, 0, stream>>>(srcs, dsts, cnt_blk, bbase, im, E, NBUK, CSTR);
  bukfine_kernel<<<NBUK, 256, 0, stream>>>(im, bbase, offs, csr, N);
  gemm1_kernel<<<(N+63)/64, 256, 0, stream>>>(x, W1h, W1l, as1w, ad1w, h1b, a_s1, a_d1, N);
  agg1_kernel<<<(N+3)/4, 256, 0, stream>>>((const unsigned int*)h1b, a_s1, a_d1, offs, csr, b1, h1a4, N);
  gemm2_kernel<<<(N+63)/64, 256, 0, stream>>>(h1a4, W2, as2w, ad2w, h2s, a_s2, a_d2, N);
  agg2_kernel<<<(N+3)/4, 256, 0, stream>>>((const unsigned int*)h2s, a_s2, a_d2, offs, csr, b2, linw, linb, out, N);
}